// Round 1
// baseline (1054.281 us; speedup 1.0000x reference)
//
#include <hip/hip_runtime.h>

// ---------------------------------------------------------------------------
// GCN stack, one workgroup (512 thr) per batch element, 2 WG/CU.
//   B=4096 N=128 U=128 H=6
// Round-5 structure (on top of round-4 register-pipelined weights):
//  - G2 re-tiled: 32 units x 64 nodes per wave (was 64x32). A-operand
//    (Y^T) LDS reads halve: 8 ds_read_b128/wave instead of 16. adjB grows
//    to [4][4] (64 VGPR), funded by SINGLE-buffering wf (prefetch during
//    G2 writes into regs dead since the preceding G1 -- program order per
//    wave, no hazard). Steady-state reg pressure unchanged (=128).
//  - epilogue reads restructured contiguous (wave w owns nodes 16w..+15,
//    lane = node x kchunk) -> removes the 8-way bank conflict.
//  - s_setprio(1) around MFMA clusters (2 anti-phased blocks/CU).
// LDS: sX + sY 32 KB each, frag-major:
//     AIDX(r,k) = (r>>4)*2048 + (k>>3)*128 + (r&15)*8 + (k&7)
// GEMM1: D=Y      (A = sX rows=nodes, B = wf regs, 64x32/wave) -> sY (Y^T)
// GEMM2: D=X'^T   (A = sY rows=units, B = adjB regs, 32x64/wave) -> sX (X')
// ---------------------------------------------------------------------------

typedef __bf16  bf16x8 __attribute__((ext_vector_type(8)));
typedef __bf16  bf16x4 __attribute__((ext_vector_type(4)));
typedef float   f32x4  __attribute__((ext_vector_type(4)));
typedef float   f32x8  __attribute__((ext_vector_type(8)));

#define AIDX(r, k)   ((((r) >> 4) << 11) + (((k) >> 3) << 7) + (((r) & 15) << 3) + ((k) & 7))
#define BIDX32(r, k) ((((r) >> 4) << 9) + (((k) >> 3) << 7) + (((r) & 15) << 3) + ((k) & 7))

__device__ __forceinline__ f32x4 mfma16(bf16x8 a, bf16x8 b, f32x4 c) {
    return __builtin_amdgcn_mfma_f32_16x16x32_bf16(a, b, c, 0, 0, 0);
}
__device__ __forceinline__ bf16x8 cvt8(float4 lo, float4 hi) {
    f32x8 f; f[0]=lo.x; f[1]=lo.y; f[2]=lo.z; f[3]=lo.w;
             f[4]=hi.x; f[5]=hi.y; f[6]=hi.z; f[7]=hi.w;
    return __builtin_convertvector(f, bf16x8);   // RNE
}
__device__ __forceinline__ bf16x4 cvt4(f32x4 v) {
    return __builtin_convertvector(v, bf16x4);
}

// ---- prep: transpose weights to bf16 in workspace -------------------------
__global__ void gcn_prep(const float* __restrict__ W_in,
                         const float* __restrict__ W_h,
                         __bf16* __restrict__ wt_in,
                         __bf16* __restrict__ wt_h) {
    int idx = blockIdx.x * 256 + threadIdx.x;
    if (idx < 4096) {
        int o = idx >> 5, i = idx & 31;
        wt_in[idx] = (i < 16) ? (__bf16)W_in[i * 128 + o] : (__bf16)0.f;
    } else {
        int j = idx - 4096;
        if (j < 98304) {
            int l = j >> 14, r = j & 16383, o = r >> 7, i = r & 127;
            wt_h[j] = (__bf16)W_h[l * 16384 + i * 128 + o];
        }
    }
}

// G1: Y = relu(X @ W_h[l] + b); A from sX (64 nodes/wave), B = wf regs;
// writes Y^T -> sY.  16 ds_read_b128 / wave.
#define G1_PHASE()                                                           \
    {                                                                        \
        f32x4 acc[4][2];                                                     \
        _Pragma("unroll") for (int rt = 0; rt < 4; ++rt) {                   \
            acc[rt][0] = (f32x4){bs0, bs0, bs0, bs0};                        \
            acc[rt][1] = (f32x4){bs1, bs1, bs1, bs1};                        \
        }                                                                    \
        __builtin_amdgcn_s_setprio(1);                                       \
        _Pragma("unroll") for (int ks = 0; ks < 4; ++ks) {                   \
            _Pragma("unroll") for (int rt = 0; rt < 4; ++rt) {               \
                bf16x8 a = *(const bf16x8*)&sX[AIDX(wm*64 + rt*16 + c, ks*32 + q*8)]; \
                acc[rt][0] = mfma16(a, wf[0][ks], acc[rt][0]);               \
                acc[rt][1] = mfma16(a, wf[1][ks], acc[rt][1]);               \
            }                                                                \
        }                                                                    \
        __builtin_amdgcn_s_setprio(0);                                       \
        _Pragma("unroll") for (int ct = 0; ct < 2; ++ct) {                   \
            int u = wn*32 + ct*16 + c;                                       \
            _Pragma("unroll") for (int rt = 0; rt < 4; ++rt) {               \
                int n0 = wm*64 + rt*16 + q*4;                                \
                f32x4 v;                                                     \
                _Pragma("unroll") for (int j = 0; j < 4; ++j)                \
                    v[j] = fmaxf(acc[rt][ct][j], 0.f);                       \
                *(bf16x4*)&sY[AIDX(u, n0)] = cvt4(v);                        \
            }                                                                \
        }                                                                    \
    }

// G2: X'^T = Y^T @ adj^T; 32 units x 64 nodes per wave.
// A from sY (8 ds_read_b128/wave, halved), B = adjB[4][4] regs; writes sX.
// DO_PRE: prefetch next layer's wf frags + biases (regs dead since G1).
#define G2_PHASE(NEXTL, DO_PRE)                                              \
    {                                                                        \
        if (DO_PRE) {                                                        \
            const __bf16* wtn = wt_h + (NEXTL) * 16384;                      \
            _Pragma("unroll") for (int ct = 0; ct < 2; ++ct)                 \
                _Pragma("unroll") for (int ks = 0; ks < 4; ++ks)             \
                    wf[ct][ks] = *(const bf16x8*)&wtn[(wn*32 + ct*16 + c)*128 + ks*32 + q*8]; \
            bs0 = b_h[(NEXTL)*128 + wn*32 + c];                              \
            bs1 = b_h[(NEXTL)*128 + wn*32 + 16 + c];                         \
        }                                                                    \
        f32x4 acc[2][4];                                                     \
        _Pragma("unroll") for (int rt = 0; rt < 2; ++rt)                     \
            _Pragma("unroll") for (int ct = 0; ct < 4; ++ct)                 \
                acc[rt][ct] = (f32x4){0.f, 0.f, 0.f, 0.f};                   \
        __builtin_amdgcn_s_setprio(1);                                       \
        _Pragma("unroll") for (int ks = 0; ks < 4; ++ks) {                   \
            _Pragma("unroll") for (int rt = 0; rt < 2; ++rt) {               \
                bf16x8 a = *(const bf16x8*)&sY[AIDX(wn*32 + rt*16 + c, ks*32 + q*8)]; \
                _Pragma("unroll") for (int ct = 0; ct < 4; ++ct)             \
                    acc[rt][ct] = mfma16(a, adjB[ct][ks], acc[rt][ct]);      \
            }                                                                \
        }                                                                    \
        __builtin_amdgcn_s_setprio(0);                                       \
        _Pragma("unroll") for (int ct = 0; ct < 4; ++ct) {                   \
            int node = wm*64 + ct*16 + c;                                    \
            _Pragma("unroll") for (int rt = 0; rt < 2; ++rt) {               \
                int u0 = wn*32 + rt*16 + q*4;                                \
                *(bf16x4*)&sX[AIDX(node, u0)] = cvt4(acc[rt][ct]);           \
            }                                                                \
        }                                                                    \
    }

__global__ __launch_bounds__(512, 4) void gcn_main(
    const int* __restrict__ pdg, const float* __restrict__ feat,
    const float* __restrict__ adj, const float* __restrict__ mask,
    const float* __restrict__ emb, const float* __restrict__ b_in,
    const float* __restrict__ b_h, const float* __restrict__ W_out,
    const float* __restrict__ b_out,
    const __bf16* __restrict__ wt_in, const __bf16* __restrict__ wt_h,
    float* __restrict__ out) {

    __shared__ __attribute__((aligned(16))) __bf16 sX[128 * 128];  // 32 KB
    __shared__ __attribute__((aligned(16))) __bf16 sY[128 * 128];  // 32 KB
    __shared__ float red[16];

    const int b    = blockIdx.x;
    const int tid  = threadIdx.x;
    const int lane = tid & 63;
    const int wave = tid >> 6;
    const int q    = lane >> 4;   // k-chunk quad / C row-quad
    const int c    = lane & 15;   // fragment row/col within 16
    const int wm   = wave >> 2;   // G1: node strip 64*wm | G2: node-col strip 64*wm
    const int wn   = wave & 3;    // G1: unit strip 32*wn | G2: unit-row strip 32*wn

    // ---- adj^T B-fragments (64 node-cols/wave) -> regs, whole kernel ------
    bf16x8 adjB[4][4];
    {
        const float* ap = adj + (size_t)b * 16384;
        #pragma unroll
        for (int ct = 0; ct < 4; ++ct) {
            const float* rp = ap + (wm * 64 + ct * 16 + c) * 128 + q * 8;
            #pragma unroll
            for (int ks = 0; ks < 4; ++ks) {
                const float4* p = (const float4*)(rp + ks * 32);
                adjB[ct][ks] = cvt8(p[0], p[1]);
            }
        }
    }

    // ---- wf single buffer: preload layer 0 frags + bias -------------------
    bf16x8 wf[2][4];
    float bs0, bs1;
    {
        #pragma unroll
        for (int ct = 0; ct < 2; ++ct)
            #pragma unroll
            for (int ks = 0; ks < 4; ++ks)
                wf[ct][ks] = *(const bf16x8*)&wt_h[(wn*32 + ct*16 + c)*128 + ks*32 + q*8];
        bs0 = b_h[wn*32 + c];
        bs1 = b_h[wn*32 + 16 + c];
    }

    // ---- stage X0 = [feat | emb | 0] frag-major (K=32) into sY region -----
    {
        int node = tid >> 2, part = tid & 3;
        bf16x8 v;
        if (part == 0) {
            const float4* f = (const float4*)(feat + ((size_t)b * 128 + node) * 8);
            v = cvt8(f[0], f[1]);
        } else if (part == 1) {
            const float4* e = (const float4*)(emb + pdg[b * 128 + node] * 8);
            v = cvt8(e[0], e[1]);
        } else {
            #pragma unroll
            for (int i = 0; i < 8; ++i) v[i] = (__bf16)0.f;
        }
        *(bf16x8*)&sY[BIDX32(node, part * 8)] = v;
    }
    __syncthreads();

    // ---- input layer: D = X1^T (M=units), A = wt_in, B = X0; -> sX --------
    {
        f32x4 acc[4][2];
        #pragma unroll
        for (int rt = 0; rt < 4; ++rt) {
            int u0 = wm * 64 + rt * 16 + q * 4;
            float4 bi = *(const float4*)&b_in[u0];
            acc[rt][0] = (f32x4){bi.x, bi.y, bi.z, bi.w};
            acc[rt][1] = acc[rt][0];
        }
        bf16x8 bx0 = *(const bf16x8*)&sY[BIDX32(wn * 32 +  0 + c, q * 8)];
        bf16x8 bx1 = *(const bf16x8*)&sY[BIDX32(wn * 32 + 16 + c, q * 8)];
        #pragma unroll
        for (int rt = 0; rt < 4; ++rt) {
            bf16x8 aw = *(const bf16x8*)&wt_in[(wm * 64 + rt * 16 + c) * 32 + q * 8];
            acc[rt][0] = mfma16(aw, bx0, acc[rt][0]);
            acc[rt][1] = mfma16(aw, bx1, acc[rt][1]);
        }
        // lane holds X1^T[u0..u0+3][node] = X1[node][4 consecutive units]
        #pragma unroll
        for (int rt = 0; rt < 4; ++rt) {
            int u0 = wm * 64 + rt * 16 + q * 4;
            #pragma unroll
            for (int ct = 0; ct < 2; ++ct) {
                int node = wn * 32 + ct * 16 + c;
                *(bf16x4*)&sX[AIDX(node, u0)] = cvt4(acc[rt][ct]);
            }
        }
    }
    __syncthreads();

    // ---- 6 hidden layers, fully unrolled, wf single-buffer prefetch -------
    G1_PHASE(); __syncthreads();
    G2_PHASE(1, 1); __syncthreads();
    G1_PHASE(); __syncthreads();
    G2_PHASE(2, 1); __syncthreads();
    G1_PHASE(); __syncthreads();
    G2_PHASE(3, 1); __syncthreads();
    G1_PHASE(); __syncthreads();
    G2_PHASE(4, 1); __syncthreads();
    G1_PHASE(); __syncthreads();
    G2_PHASE(5, 1); __syncthreads();
    G1_PHASE(); __syncthreads();
    G2_PHASE(0, 0); __syncthreads();

    // ---- epilogue: masked mean pool + W_out dot (conflict-free reads) -----
    {
        int node = wave * 16 + (lane & 15);   // wave owns 16 nodes
        int kc   = lane >> 4;                 // 4 k-chunks of 8 per t-step
        float part = 0.f;
        #pragma unroll
        for (int t = 0; t < 4; ++t) {
            bf16x8 v = *(const bf16x8*)&sX[AIDX(node, t * 32 + kc * 8)];
            const float* wo = W_out + t * 32 + kc * 8;
            #pragma unroll
            for (int j = 0; j < 8; ++j) part += (float)v[j] * wo[j];
        }
        // reduce over k-chunks (lanes differing in kc share the same node)
        part += __shfl_xor(part, 16);
        part += __shfl_xor(part, 32);
        float mv = mask[b * 128 + node];
        part *= mv;
        float msum = mv;
        // reduce over the 16 nodes of this wave (xor stays within kc group)
        #pragma unroll
        for (int off = 8; off >= 1; off >>= 1) {
            part += __shfl_xor(part, off);
            msum += __shfl_xor(msum, off);
        }
        if (lane == 0) { red[wave] = part; red[8 + wave] = msum; }
        __syncthreads();
        if (tid == 0) {
            float s = 0.f, ms = 0.f;
            #pragma unroll
            for (int i = 0; i < 8; ++i) { s += red[i]; ms += red[8 + i]; }
            out[b] = s / fmaxf(ms, 1.f) + b_out[0];
        }
    }
}

extern "C" void kernel_launch(void* const* d_in, const int* in_sizes, int n_in,
                              void* d_out, int out_size, void* d_ws, size_t ws_size,
                              hipStream_t stream) {
    const int*   pdg   = (const int*)d_in[0];
    const float* feat  = (const float*)d_in[1];
    const float* adj   = (const float*)d_in[2];
    const float* mask  = (const float*)d_in[3];
    const float* emb   = (const float*)d_in[4];
    const float* W_in  = (const float*)d_in[5];
    const float* b_in  = (const float*)d_in[6];
    const float* W_h   = (const float*)d_in[7];
    const float* b_h   = (const float*)d_in[8];
    const float* W_out = (const float*)d_in[9];
    const float* b_out = (const float*)d_in[10];

    __bf16* wt_in = (__bf16*)d_ws;          // 128*32 bf16
    __bf16* wt_h  = wt_in + 4096;           // 6*128*128 bf16

    gcn_prep<<<400, 256, 0, stream>>>(W_in, W_h, wt_in, wt_h);
    gcn_main<<<4096, 512, 0, stream>>>(pdg, feat, adj, mask, emb, b_in, b_h,
                                       W_out, b_out, wt_in, wt_h, (float*)d_out);
}

// Round 2
// 584.443 us; speedup vs baseline: 1.8039x; 1.8039x over previous
//
#include <hip/hip_runtime.h>

// ---------------------------------------------------------------------------
// GCN stack, one workgroup (512 thr) per batch element, 2 WG/CU.
//   B=4096 N=128 U=128 H=6
// Round-6 = round-4 structure (known 371us) + register-safe deltas only:
//  - wf SINGLE buffer [2][4] (32 VGPR): next layer's frags+bias prefetched
//    at the start of G2 into registers dead since the preceding G1.
//    Peak live set: adjB 32 + wf 32 + acc 32 + misc ~16 = ~112 < 128 cap.
//    (Round-5's adjB[4][4]=64 retile spilled: WRITE_SIZE 134KB -> 1.04GB.)
//  - s_setprio(1) around MFMA clusters (2 co-resident blocks per CU are
//    independent / anti-phased -> m191 regime).
//  - conflict-free contiguous epilogue (verified in round 5).
// LDS: sX + sY 32 KB each, frag-major:
//     AIDX(r,k) = (r>>4)*2048 + (k>>3)*128 + (r&15)*8 + (k&7)
// GEMM1: D=Y      (A = sX rows=nodes, B = wf regs, 64x32/wave)  -> sY (Y^T)
// GEMM2: D=X'^T   (A = sY rows=units, B = adjB regs, 64x32/wave)-> sX (X')
// ---------------------------------------------------------------------------

typedef __bf16  bf16x8 __attribute__((ext_vector_type(8)));
typedef __bf16  bf16x4 __attribute__((ext_vector_type(4)));
typedef float   f32x4  __attribute__((ext_vector_type(4)));
typedef float   f32x8  __attribute__((ext_vector_type(8)));

#define AIDX(r, k)   ((((r) >> 4) << 11) + (((k) >> 3) << 7) + (((r) & 15) << 3) + ((k) & 7))
#define BIDX32(r, k) ((((r) >> 4) << 9) + (((k) >> 3) << 7) + (((r) & 15) << 3) + ((k) & 7))

__device__ __forceinline__ f32x4 mfma16(bf16x8 a, bf16x8 b, f32x4 c) {
    return __builtin_amdgcn_mfma_f32_16x16x32_bf16(a, b, c, 0, 0, 0);
}
__device__ __forceinline__ bf16x8 cvt8(float4 lo, float4 hi) {
    f32x8 f; f[0]=lo.x; f[1]=lo.y; f[2]=lo.z; f[3]=lo.w;
             f[4]=hi.x; f[5]=hi.y; f[6]=hi.z; f[7]=hi.w;
    return __builtin_convertvector(f, bf16x8);   // RNE
}
__device__ __forceinline__ bf16x4 cvt4(f32x4 v) {
    return __builtin_convertvector(v, bf16x4);
}

// ---- prep: transpose weights to bf16 in workspace -------------------------
__global__ void gcn_prep(const float* __restrict__ W_in,
                         const float* __restrict__ W_h,
                         __bf16* __restrict__ wt_in,
                         __bf16* __restrict__ wt_h) {
    int idx = blockIdx.x * 256 + threadIdx.x;
    if (idx < 4096) {
        int o = idx >> 5, i = idx & 31;
        wt_in[idx] = (i < 16) ? (__bf16)W_in[i * 128 + o] : (__bf16)0.f;
    } else {
        int j = idx - 4096;
        if (j < 98304) {
            int l = j >> 14, r = j & 16383, o = r >> 7, i = r & 127;
            wt_h[j] = (__bf16)W_h[l * 16384 + i * 128 + o];
        }
    }
}

// G1: Y = relu(X @ W_h[l] + b); A from sX (64 nodes/wave), B = wf regs;
// writes Y^T -> sY.  16 ds_read_b128 / wave.
#define G1_PHASE()                                                           \
    {                                                                        \
        f32x4 acc[4][2];                                                     \
        _Pragma("unroll") for (int rt = 0; rt < 4; ++rt) {                   \
            acc[rt][0] = (f32x4){bs0, bs0, bs0, bs0};                        \
            acc[rt][1] = (f32x4){bs1, bs1, bs1, bs1};                        \
        }                                                                    \
        __builtin_amdgcn_s_setprio(1);                                       \
        _Pragma("unroll") for (int ks = 0; ks < 4; ++ks) {                   \
            _Pragma("unroll") for (int rt = 0; rt < 4; ++rt) {               \
                bf16x8 a = *(const bf16x8*)&sX[AIDX(wm*64 + rt*16 + c, ks*32 + q*8)]; \
                acc[rt][0] = mfma16(a, wf[0][ks], acc[rt][0]);               \
                acc[rt][1] = mfma16(a, wf[1][ks], acc[rt][1]);               \
            }                                                                \
        }                                                                    \
        __builtin_amdgcn_s_setprio(0);                                       \
        _Pragma("unroll") for (int ct = 0; ct < 2; ++ct) {                   \
            int u = wn*32 + ct*16 + c;                                       \
            _Pragma("unroll") for (int rt = 0; rt < 4; ++rt) {               \
                int n0 = wm*64 + rt*16 + q*4;                                \
                f32x4 v;                                                     \
                _Pragma("unroll") for (int j = 0; j < 4; ++j)                \
                    v[j] = fmaxf(acc[rt][ct][j], 0.f);                       \
                *(bf16x4*)&sY[AIDX(u, n0)] = cvt4(v);                        \
            }                                                                \
        }                                                                    \
    }

// G2: X'^T = Y^T @ adj^T; 64 units x 32 nodes per wave (round-4 tiling).
// A from sY (16 ds_read_b128/wave), B = adjB[2][4] regs; writes sX.
// DO_PRE: prefetch next layer's wf frags + biases into the wf single
// buffer -- those registers are dead since the preceding G1 (program
// order per wave), and G2's MFMAs use only adjB. No hazard.
#define G2_PHASE(NEXTL, DO_PRE)                                              \
    {                                                                        \
        if (DO_PRE) {                                                        \
            const __bf16* wtn = wt_h + (NEXTL) * 16384;                      \
            _Pragma("unroll") for (int ct = 0; ct < 2; ++ct)                 \
                _Pragma("unroll") for (int ks = 0; ks < 4; ++ks)             \
                    wf[ct][ks] = *(const bf16x8*)&wtn[(wn*32 + ct*16 + c)*128 + ks*32 + q*8]; \
            bs0 = b_h[(NEXTL)*128 + wn*32 + c];                              \
            bs1 = b_h[(NEXTL)*128 + wn*32 + 16 + c];                         \
        }                                                                    \
        f32x4 acc[4][2];                                                     \
        _Pragma("unroll") for (int rt = 0; rt < 4; ++rt) {                   \
            acc[rt][0] = (f32x4){0.f, 0.f, 0.f, 0.f};                        \
            acc[rt][1] = (f32x4){0.f, 0.f, 0.f, 0.f};                        \
        }                                                                    \
        __builtin_amdgcn_s_setprio(1);                                       \
        _Pragma("unroll") for (int ks = 0; ks < 4; ++ks) {                   \
            _Pragma("unroll") for (int rt = 0; rt < 4; ++rt) {               \
                bf16x8 a = *(const bf16x8*)&sY[AIDX(wm*64 + rt*16 + c, ks*32 + q*8)]; \
                acc[rt][0] = mfma16(a, adjB[0][ks], acc[rt][0]);             \
                acc[rt][1] = mfma16(a, adjB[1][ks], acc[rt][1]);             \
            }                                                                \
        }                                                                    \
        __builtin_amdgcn_s_setprio(0);                                       \
        _Pragma("unroll") for (int ct = 0; ct < 2; ++ct) {                   \
            int node = wn*32 + ct*16 + c;                                    \
            _Pragma("unroll") for (int rt = 0; rt < 4; ++rt) {               \
                int u0 = wm*64 + rt*16 + q*4;                                \
                *(bf16x4*)&sX[AIDX(node, u0)] = cvt4(acc[rt][ct]);           \
            }                                                                \
        }                                                                    \
    }

__global__ __launch_bounds__(512, 4) void gcn_main(
    const int* __restrict__ pdg, const float* __restrict__ feat,
    const float* __restrict__ adj, const float* __restrict__ mask,
    const float* __restrict__ emb, const float* __restrict__ b_in,
    const float* __restrict__ b_h, const float* __restrict__ W_out,
    const float* __restrict__ b_out,
    const __bf16* __restrict__ wt_in, const __bf16* __restrict__ wt_h,
    float* __restrict__ out) {

    __shared__ __attribute__((aligned(16))) __bf16 sX[128 * 128];  // 32 KB
    __shared__ __attribute__((aligned(16))) __bf16 sY[128 * 128];  // 32 KB
    __shared__ float red[16];

    const int b    = blockIdx.x;
    const int tid  = threadIdx.x;
    const int lane = tid & 63;
    const int wave = tid >> 6;
    const int q    = lane >> 4;   // k-chunk quad / C row-quad
    const int c    = lane & 15;   // fragment row/col within 16
    const int wm   = wave >> 2;   // M strip: 64*wm   (2 groups)
    const int wn   = wave & 3;    // N strip: 32*wn   (4 groups)

    // ---- adj^T B-fragments (32 node-cols/wave) -> regs, whole kernel ------
    bf16x8 adjB[2][4];
    {
        const float* ap = adj + (size_t)b * 16384;
        #pragma unroll
        for (int ct = 0; ct < 2; ++ct) {
            const float* rp = ap + (wn * 32 + ct * 16 + c) * 128 + q * 8;
            #pragma unroll
            for (int ks = 0; ks < 4; ++ks) {
                const float4* p = (const float4*)(rp + ks * 32);
                adjB[ct][ks] = cvt8(p[0], p[1]);
            }
        }
    }

    // ---- wf single buffer: preload layer 0 frags + bias -------------------
    bf16x8 wf[2][4];
    float bs0, bs1;
    {
        #pragma unroll
        for (int ct = 0; ct < 2; ++ct)
            #pragma unroll
            for (int ks = 0; ks < 4; ++ks)
                wf[ct][ks] = *(const bf16x8*)&wt_h[(wn*32 + ct*16 + c)*128 + ks*32 + q*8];
        bs0 = b_h[wn*32 + c];
        bs1 = b_h[wn*32 + 16 + c];
    }

    // ---- stage X0 = [feat | emb | 0] frag-major (K=32) into sY region -----
    {
        int node = tid >> 2, part = tid & 3;
        bf16x8 v;
        if (part == 0) {
            const float4* f = (const float4*)(feat + ((size_t)b * 128 + node) * 8);
            v = cvt8(f[0], f[1]);
        } else if (part == 1) {
            const float4* e = (const float4*)(emb + pdg[b * 128 + node] * 8);
            v = cvt8(e[0], e[1]);
        } else {
            #pragma unroll
            for (int i = 0; i < 8; ++i) v[i] = (__bf16)0.f;
        }
        *(bf16x8*)&sY[BIDX32(node, part * 8)] = v;
    }
    __syncthreads();

    // ---- input layer: D = X1^T (M=units), A = wt_in, B = X0; -> sX --------
    {
        f32x4 acc[4][2];
        #pragma unroll
        for (int rt = 0; rt < 4; ++rt) {
            int u0 = wm * 64 + rt * 16 + q * 4;
            float4 bi = *(const float4*)&b_in[u0];
            acc[rt][0] = (f32x4){bi.x, bi.y, bi.z, bi.w};
            acc[rt][1] = acc[rt][0];
        }
        bf16x8 bx0 = *(const bf16x8*)&sY[BIDX32(wn * 32 +  0 + c, q * 8)];
        bf16x8 bx1 = *(const bf16x8*)&sY[BIDX32(wn * 32 + 16 + c, q * 8)];
        #pragma unroll
        for (int rt = 0; rt < 4; ++rt) {
            bf16x8 aw = *(const bf16x8*)&wt_in[(wm * 64 + rt * 16 + c) * 32 + q * 8];
            acc[rt][0] = mfma16(aw, bx0, acc[rt][0]);
            acc[rt][1] = mfma16(aw, bx1, acc[rt][1]);
        }
        // lane holds X1^T[u0..u0+3][node] = X1[node][4 consecutive units]
        #pragma unroll
        for (int rt = 0; rt < 4; ++rt) {
            int u0 = wm * 64 + rt * 16 + q * 4;
            #pragma unroll
            for (int ct = 0; ct < 2; ++ct) {
                int node = wn * 32 + ct * 16 + c;
                *(bf16x4*)&sX[AIDX(node, u0)] = cvt4(acc[rt][ct]);
            }
        }
    }
    __syncthreads();

    // ---- 6 hidden layers, fully unrolled, wf single-buffer prefetch -------
    G1_PHASE(); __syncthreads();
    G2_PHASE(1, 1); __syncthreads();
    G1_PHASE(); __syncthreads();
    G2_PHASE(2, 1); __syncthreads();
    G1_PHASE(); __syncthreads();
    G2_PHASE(3, 1); __syncthreads();
    G1_PHASE(); __syncthreads();
    G2_PHASE(4, 1); __syncthreads();
    G1_PHASE(); __syncthreads();
    G2_PHASE(5, 1); __syncthreads();
    G1_PHASE(); __syncthreads();
    G2_PHASE(0, 0); __syncthreads();

    // ---- epilogue: masked mean pool + W_out dot (contiguous reads) --------
    {
        int node = wave * 16 + (lane & 15);   // wave owns 16 nodes
        int kc   = lane >> 4;                 // 4 k-chunks of 8 per t-step
        float part = 0.f;
        #pragma unroll
        for (int t = 0; t < 4; ++t) {
            bf16x8 v = *(const bf16x8*)&sX[AIDX(node, t * 32 + kc * 8)];
            const float* wo = W_out + t * 32 + kc * 8;
            #pragma unroll
            for (int j = 0; j < 8; ++j) part += (float)v[j] * wo[j];
        }
        // reduce over k-chunks (lanes differing in kc share the same node)
        part += __shfl_xor(part, 16);
        part += __shfl_xor(part, 32);
        float mv = mask[b * 128 + node];
        part *= mv;
        float msum = mv;
        // reduce over the 16 nodes of this wave (xor stays within kc group)
        #pragma unroll
        for (int off = 8; off >= 1; off >>= 1) {
            part += __shfl_xor(part, off);
            msum += __shfl_xor(msum, off);
        }
        if (lane == 0) { red[wave] = part; red[8 + wave] = msum; }
        __syncthreads();
        if (tid == 0) {
            float s = 0.f, ms = 0.f;
            #pragma unroll
            for (int i = 0; i < 8; ++i) { s += red[i]; ms += red[8 + i]; }
            out[b] = s / fmaxf(ms, 1.f) + b_out[0];
        }
    }
}

extern "C" void kernel_launch(void* const* d_in, const int* in_sizes, int n_in,
                              void* d_out, int out_size, void* d_ws, size_t ws_size,
                              hipStream_t stream) {
    const int*   pdg   = (const int*)d_in[0];
    const float* feat  = (const float*)d_in[1];
    const float* adj   = (const float*)d_in[2];
    const float* mask  = (const float*)d_in[3];
    const float* emb   = (const float*)d_in[4];
    const float* W_in  = (const float*)d_in[5];
    const float* b_in  = (const float*)d_in[6];
    const float* W_h   = (const float*)d_in[7];
    const float* b_h   = (const float*)d_in[8];
    const float* W_out = (const float*)d_in[9];
    const float* b_out = (const float*)d_in[10];

    __bf16* wt_in = (__bf16*)d_ws;          // 128*32 bf16
    __bf16* wt_h  = wt_in + 4096;           // 6*128*128 bf16

    gcn_prep<<<400, 256, 0, stream>>>(W_in, W_h, wt_in, wt_h);
    gcn_main<<<4096, 512, 0, stream>>>(pdg, feat, adj, mask, emb, b_in, b_h,
                                       W_out, b_out, wt_in, wt_h, (float*)d_out);
}